// Round 12
// baseline (84.981 us; speedup 1.0000x reference)
//
#include <hip/hip_runtime.h>
#include <hip/hip_bf16.h>
#include <math.h>

#define NROWS 8192
#define DIM   768
#define NKB   (DIM / 64)         // 12 k-chunks of 64
#define FCH   8192               // fp8 chunk: 128 rows x 64 cols = 8 KB
#define FPAN  (NKB * FCH)        // fp8 panel: 128 rows x 768 = 98304 B
#define NT128 (NROWS / 128)      // 64 row-blocks (chunk granularity)
#define NT256 (NROWS / 256)      // 32 tile-panels of 256
#define NTIL2 (NT256 * (NT256 + 1) / 2)    // 528 upper-tri 256^2 tiles
#define PACK8B ((size_t)NT128 * FPAN)      // 6.29 MB

typedef __attribute__((ext_vector_type(4))) float  f32x4;
typedef __attribute__((ext_vector_type(8))) __bf16 bf16x8;
typedef __attribute__((ext_vector_type(4))) __bf16 bf16x4;
typedef __attribute__((ext_vector_type(2))) long   longx2;

__device__ __forceinline__ void gload_lds16(const void* g, void* l) {
  __builtin_amdgcn_global_load_lds(
      (const __attribute__((address_space(1))) void*)g,
      (__attribute__((address_space(3))) void*)l, 16, 0, 0);
}

// ---------------------------------------------------------------------------
// Kernel A (UNCHANGED — validated R7/R11, 0 LDS conflicts downstream):
// fused fp8-pack + prep into INTERLEAVED, swizzle-pre-applied chunk layout.
//   chunk(rb, kb) = 128 rows x 64 k-bytes; k = ks*32+g*8+b stored at
//   pos = g*16+ks*8+b; off = (r*64+pos) ^ (((r>>1)&3)<<4).
// ---------------------------------------------------------------------------
__global__ __launch_bounds__(256) void koleo_pack8(const float* __restrict__ X,
                                                   float* __restrict__ sq,
                                                   unsigned int* __restrict__ minbits,
                                                   char* __restrict__ xbf) {
  const int row  = blockIdx.x * 4 + (threadIdx.x >> 6);
  const int lane = threadIdx.x & 63;
  const int rb = row >> 7, r = row & 127;
  const float* xr = X + (size_t)row * DIM;
  float s = 0.f;
#pragma unroll
  for (int i = 0; i < 3; ++i) {            // 768 = 3 * 64 lanes * 4 floats
    const int c0 = lane * 4 + i * 256;
    f32x4 v = *(const f32x4*)(xr + c0);
    s += v.x * v.x + v.y * v.y + v.z * v.z + v.w * v.w;
    int pk = __builtin_amdgcn_cvt_pk_fp8_f32(v.x, v.y, 0, false);
    pk     = __builtin_amdgcn_cvt_pk_fp8_f32(v.z, v.w, pk, true);
    const int kb = c0 >> 6;
    const int c  = c0 & 63;
    const int ks = c >> 5;
    const int g  = (c >> 3) & 3;
    const int bb = c & 7;
    const int pos = g * 16 + ks * 8 + bb;
    const int off = (r * 64 + pos) ^ (((r >> 1) & 3) << 4);
    *(int*)(xbf + (size_t)rb * FPAN + (size_t)kb * FCH + off) = pk;
  }
#pragma unroll
  for (int m = 32; m >= 1; m >>= 1) s += __shfl_xor(s, m, 64);
  if (lane == 0) {
    sq[row]      = s;
    minbits[row] = 0x7F800000u;            // +inf
  }
}

// ---------------------------------------------------------------------------
// Kernel B: 256x256 upper-triangular Gram tiles, fp8, 16 waves (4x4 of
// 64x64), BK=64, 2-phase dbuf. EPOCH CONSOLIDATION vs R7/R11: 4x fewer
// barrier epochs (6336 vs 24960), 4x more MFMA per epoch — attacks the
// measured ~1400-cyc-per-epoch serial skeleton, not a pipe.
// Per epoch: issue next chunk's 2 gloads/wave FIRST, 8x ds_read_b128,
// 32 MFMA, vmcnt(0), one barrier.
// LDS: 2 buffers x {A0,A1,B0,B1 chunks of 8KB} = 65536 B -> 1 block/CU,
// full 16-wave residency at VGPR<=128 (__launch_bounds__(1024,4)).
// Tile ordering = L2 segments over 32 panels: [T0 tri16:136][4 bands 16x4:
// 256][T1 tri16:136]; footprint <= 3.75 MB per segment.
// ---------------------------------------------------------------------------
__global__ __launch_bounds__(1024, 4) void koleo_tile256(const char* __restrict__ xbf,
                                                         const float* __restrict__ sq,
                                                         unsigned int* __restrict__ minbits) {
  extern __shared__ char lds[];            // 65536 bytes

  // segment-ordered tile map (panels of 256 rows)
  const int b = blockIdx.x;
  int ti, tj;
  if (b < 136) {                           // T0: panels [0,16)
    int rem = b, rl = 16; ti = 0;
    while (rem >= rl) { rem -= rl; ++ti; --rl; }
    tj = ti + rem;
  } else if (b < 392) {                    // bands ti:[0,16) x tj:[16+4q,20+4q)
    const int q = (b - 136) >> 6, rr = (b - 136) & 63;
    ti = rr >> 2; tj = 16 + q * 4 + (rr & 3);
  } else {                                 // T1: panels [16,32)
    int rem = b - 392, rl = 16; ti = 16;
    while (rem >= rl) { rem -= rl; ++ti; --rl; }
    tj = ti + rem;
  }
  const int i0 = ti * 256, j0 = tj * 256;

  const int tid  = threadIdx.x;
  const int lane = tid & 63;
  const int wave = tid >> 6;               // 0..15
  const int wr   = wave >> 2;              // 0..3 row 64-slice
  const int wc   = wave & 3;               // 0..3 col 64-slice
  const int g16  = (lane >> 4) * 16;       // fragment 16B group offset

  // staging role: chunk c = wave>>2 (A0,A1,B0,B1), part = wave&3 (2KB each)
  const int sc   = wave >> 2;
  const int spart= wave & 3;
  const int srb  = (sc < 2) ? (2 * ti + sc) : (2 * tj + (sc - 2));
  const char* sbase = xbf + (size_t)srb * FPAN + spart * 2048 + lane * 16;
  const int sdst = sc * 8192 + spart * 2048;

  f32x4 acc[4][4] = {};

  // ---- prologue: stage K-chunk 0 into buffer 0 ---------------------------
  gload_lds16(sbase,        lds + sdst);
  gload_lds16(sbase + 1024, lds + sdst + 1024);
  asm volatile("s_waitcnt vmcnt(0)" ::: "memory");
  __builtin_amdgcn_s_barrier();

  // ---- main K-loop: one barrier per chunk epoch ---------------------------
  for (int t = 0; t < NKB; ++t) {
    char* buf  = lds + (t & 1) * 32768;
    char* nbuf = lds + ((t + 1) & 1) * 32768;
    const bool more = (t + 1 < NKB);

    if (more) {                            // issue next-chunk staging FIRST
      const char* s = sbase + (size_t)(t + 1) * FCH;
      gload_lds16(s,        nbuf + sdst);
      gload_lds16(s + 1024, nbuf + sdst + 1024);
    }

    // 8x ds_read_b128: each 16B = [ks0 frag | ks1 frag] for one row
    longx2 aP[4], bP[4];
#pragma unroll
    for (int m = 0; m < 4; ++m) {
      const int r256 = wr * 64 + m * 16 + (lane & 15);
      const int h = r256 >> 7, rr2 = r256 & 127;
      aP[m] = *(const longx2*)(buf + h * 8192 +
                ((rr2 * 64 + g16) ^ (((rr2 >> 1) & 3) << 4)));
      const int c256 = wc * 64 + m * 16 + (lane & 15);
      const int hb = c256 >> 7, rb2 = c256 & 127;
      bP[m] = *(const longx2*)(buf + 16384 + hb * 8192 +
                ((rb2 * 64 + g16) ^ (((rb2 >> 1) & 3) << 4)));
    }
#pragma unroll
    for (int ks = 0; ks < 2; ++ks)
#pragma unroll
      for (int m = 0; m < 4; ++m)
#pragma unroll
        for (int n = 0; n < 4; ++n)
          acc[m][n] = __builtin_amdgcn_mfma_f32_16x16x32_fp8_fp8(aP[m][ks], bP[n][ks], acc[m][n], 0, 0, 0);

    if (more) asm volatile("s_waitcnt vmcnt(0)" ::: "memory");
    __builtin_amdgcn_s_barrier();
  }

  // ---- epilogue: d2, diagonal mask, row-min + col-min, atomicMin ----------
  // C/D layout (m89, dtype-independent): col = lane&15, row = (lane>>4)*4+reg
  const int cg = lane >> 4;
  const int cl = lane & 15;
  float sqj[4], colmin[4];
#pragma unroll
  for (int n = 0; n < 4; ++n) {
    sqj[n]    = sq[j0 + wc * 64 + n * 16 + cl];
    colmin[n] = INFINITY;
  }
#pragma unroll
  for (int m = 0; m < 4; ++m) {
#pragma unroll
    for (int r = 0; r < 4; ++r) {
      const int gi = i0 + wr * 64 + m * 16 + cg * 4 + r;
      const float si = sq[gi];
      float rowmin = INFINITY;
#pragma unroll
      for (int n = 0; n < 4; ++n) {
        const int gj = j0 + wc * 64 + n * 16 + cl;
        float d2 = si + sqj[n] - 2.0f * acc[m][n][r];
        d2 = fmaxf(d2, 0.0f);
        if (gi == gj) d2 = INFINITY;
        rowmin    = fminf(rowmin, d2);
        colmin[n] = fminf(colmin[n], d2);
      }
      rowmin = fminf(rowmin, __shfl_xor(rowmin, 1, 64));
      rowmin = fminf(rowmin, __shfl_xor(rowmin, 2, 64));
      rowmin = fminf(rowmin, __shfl_xor(rowmin, 4, 64));
      rowmin = fminf(rowmin, __shfl_xor(rowmin, 8, 64));
      if (cl == 0)
        atomicMin(minbits + gi, __float_as_uint(rowmin));
    }
  }
  if (ti != tj) {
#pragma unroll
    for (int n = 0; n < 4; ++n) {
      float cm = colmin[n];
      cm = fminf(cm, __shfl_xor(cm, 16, 64));
      cm = fminf(cm, __shfl_xor(cm, 32, 64));
      if (cg == 0)
        atomicMin(minbits + j0 + wc * 64 + n * 16 + cl, __float_as_uint(cm));
    }
  }
}

// ---------------------------------------------------------------------------
// Fallback (ws too small): bf16 f32-load + in-loop cvt staging, 128^2 tiles.
// ---------------------------------------------------------------------------
__global__ __launch_bounds__(256) void koleo_prep_fb(const float* __restrict__ X,
                                                     float* __restrict__ sq,
                                                     unsigned int* __restrict__ minbits) {
  const int row  = blockIdx.x * 4 + (threadIdx.x >> 6);
  const int lane = threadIdx.x & 63;
  const float* xr = X + (size_t)row * DIM;
  float s = 0.f;
#pragma unroll
  for (int i = 0; i < 3; ++i) {
    f32x4 v = *(const f32x4*)(xr + lane * 4 + i * 256);
    s += v.x * v.x + v.y * v.y + v.z * v.z + v.w * v.w;
  }
#pragma unroll
  for (int m = 32; m >= 1; m >>= 1) s += __shfl_xor(s, m, 64);
  if (lane == 0) { sq[row] = s; minbits[row] = 0x7F800000u; }
}

__global__ __launch_bounds__(256) void koleo_tile_fb(const float* __restrict__ X,
                                                     const float* __restrict__ sq,
                                                     unsigned int* __restrict__ minbits) {
  __shared__ __align__(16) char sA[16384];
  __shared__ __align__(16) char sB[16384];
  int rem = blockIdx.x, ti = 0, rowlen = NT128;
  while (rem >= rowlen) { rem -= rowlen; ++ti; --rowlen; }
  const int tj = ti + rem;
  const int i0 = ti * 128, j0 = tj * 128;
  const int tid = threadIdx.x, lane = tid & 63, wave = tid >> 6;
  const int wr = wave >> 1, wc = wave & 1;
  f32x4 acc[4][4] = {};
  for (int k0 = 0; k0 < DIM; k0 += 64) {
    __syncthreads();
#pragma unroll
    for (int it = 0; it < 8; ++it) {
      const int idx = tid + it * 256;
      const int r = idx >> 4, c4 = idx & 15;
      f32x4 va = *(const f32x4*)(X + (size_t)(i0 + r) * DIM + k0 + c4 * 4);
      f32x4 vb = *(const f32x4*)(X + (size_t)(j0 + r) * DIM + k0 + c4 * 4);
      bf16x4 ha, hb;
      ha[0] = (__bf16)va.x; ha[1] = (__bf16)va.y; ha[2] = (__bf16)va.z; ha[3] = (__bf16)va.w;
      hb[0] = (__bf16)vb.x; hb[1] = (__bf16)vb.y; hb[2] = (__bf16)vb.z; hb[3] = (__bf16)vb.w;
      int off = (r * 128 + c4 * 8) ^ ((r & 7) << 4);
      *(bf16x4*)(sA + off) = ha;
      *(bf16x4*)(sB + off) = hb;
    }
    __syncthreads();
#pragma unroll
    for (int ks = 0; ks < 2; ++ks) {
      bf16x8 af[4], bfr[4];
#pragma unroll
      for (int m = 0; m < 4; ++m) {
        const int ra = wr * 64 + m * 16 + (lane & 15);
        af[m]  = *(const bf16x8*)(sA + ((ra * 128 + ks * 64 + (lane >> 4) * 16) ^ ((ra & 7) << 4)));
        const int rb2 = wc * 64 + m * 16 + (lane & 15);
        bfr[m] = *(const bf16x8*)(sB + ((rb2 * 128 + ks * 64 + (lane >> 4) * 16) ^ ((rb2 & 7) << 4)));
      }
#pragma unroll
      for (int m = 0; m < 4; ++m)
#pragma unroll
        for (int n = 0; n < 4; ++n)
          acc[m][n] = __builtin_amdgcn_mfma_f32_16x16x32_bf16(af[m], bfr[n], acc[m][n], 0, 0, 0);
    }
  }
  const int cg = lane >> 4, cl = lane & 15;
  float sqj[4], colmin[4];
#pragma unroll
  for (int n = 0; n < 4; ++n) { sqj[n] = sq[j0 + wc * 64 + n * 16 + cl]; colmin[n] = INFINITY; }
#pragma unroll
  for (int m = 0; m < 4; ++m) {
#pragma unroll
    for (int r = 0; r < 4; ++r) {
      const int gi = i0 + wr * 64 + m * 16 + cg * 4 + r;
      const float si = sq[gi];
      float rowmin = INFINITY;
#pragma unroll
      for (int n = 0; n < 4; ++n) {
        const int gj = j0 + wc * 64 + n * 16 + cl;
        float d2 = si + sqj[n] - 2.0f * acc[m][n][r];
        d2 = fmaxf(d2, 0.0f);
        if (gi == gj) d2 = INFINITY;
        rowmin = fminf(rowmin, d2);
        colmin[n] = fminf(colmin[n], d2);
      }
      rowmin = fminf(rowmin, __shfl_xor(rowmin, 1, 64));
      rowmin = fminf(rowmin, __shfl_xor(rowmin, 2, 64));
      rowmin = fminf(rowmin, __shfl_xor(rowmin, 4, 64));
      rowmin = fminf(rowmin, __shfl_xor(rowmin, 8, 64));
      if (cl == 0) atomicMin(minbits + gi, __float_as_uint(rowmin));
    }
  }
  if (ti != tj) {
#pragma unroll
    for (int n = 0; n < 4; ++n) {
      float cm = colmin[n];
      cm = fminf(cm, __shfl_xor(cm, 16, 64));
      cm = fminf(cm, __shfl_xor(cm, 32, 64));
      if (cg == 0) atomicMin(minbits + j0 + wc * 64 + n * 16 + cl, __float_as_uint(cm));
    }
  }
}

// ---------------------------------------------------------------------------
// Final: loss = -mean(log(sqrt(min_d2) + eps)), single block
// ---------------------------------------------------------------------------
__global__ __launch_bounds__(1024) void koleo_final(const unsigned int* __restrict__ minbits,
                                                    float* __restrict__ out) {
  __shared__ float wsum[16];
  float s = 0.f;
  for (int i = threadIdx.x; i < NROWS; i += 1024) {
    float d2 = __uint_as_float(minbits[i]);
    s += logf(sqrtf(d2) + 1e-8f);
  }
#pragma unroll
  for (int m = 32; m >= 1; m >>= 1) s += __shfl_xor(s, m, 64);
  const int wv = threadIdx.x >> 6, ln = threadIdx.x & 63;
  if (ln == 0) wsum[wv] = s;
  __syncthreads();
  if (wv == 0) {
    float t = (ln < 16) ? wsum[ln] : 0.f;
#pragma unroll
    for (int m = 8; m >= 1; m >>= 1) t += __shfl_xor(t, m, 64);
    if (ln == 0) out[0] = -t / (float)NROWS;
  }
}

// ---------------------------------------------------------------------------
extern "C" void kernel_launch(void* const* d_in, const int* in_sizes, int n_in,
                              void* d_out, int out_size, void* d_ws, size_t ws_size,
                              hipStream_t stream) {
  const float* X = (const float*)d_in[0];
  float* out = (float*)d_out;
  unsigned int* minbits = (unsigned int*)d_ws;                       // 32 KB
  float* sq = (float*)((char*)d_ws + NROWS * sizeof(unsigned int));  // 32 KB
  char* xbf = (char*)d_ws + 65536;                                   // 6.29 MB

  const size_t need = 65536 + PACK8B;
  if (ws_size >= need) {
    koleo_pack8<<<NROWS / 4, 256, 0, stream>>>(X, sq, minbits, xbf);
    koleo_tile256<<<NTIL2, 1024, 65536, stream>>>(xbf, sq, minbits);
  } else {
    koleo_prep_fb<<<NROWS / 4, 256, 0, stream>>>(X, sq, minbits);
    koleo_tile_fb<<<NT128 * (NT128 + 1) / 2, 256, 0, stream>>>(X, sq, minbits);
  }
  koleo_final<<<1, 1024, 0, stream>>>(minbits, out);
}

// Round 13
// 66.475 us; speedup vs baseline: 1.2784x; 1.2784x over previous
//
#include <hip/hip_runtime.h>
#include <hip/hip_bf16.h>
#include <math.h>

#define NROWS 8192
#define DIM   768
#define NKB   (DIM / 64)         // 12 k-chunks of 64
#define FCH   8192               // fp8 chunk: 128 rows x 64 cols = 8 KB
#define FPAN  (NKB * FCH)        // fp8 panel: 128 rows x 768 = 98304 B
#define NT128 (NROWS / 128)      // 64 row-blocks (chunk granularity)
#define NTILES (NT128 * (NT128 + 1) / 2)   // 2080 (fallback grid)
#define NTIL3 1056               // 256x128 tiles, q >= 2p
#define PACK8B ((size_t)NT128 * FPAN)      // 6.29 MB
#define LDSB  49152              // 2 x 24 KB

typedef __attribute__((ext_vector_type(4))) float  f32x4;
typedef __attribute__((ext_vector_type(8))) __bf16 bf16x8;
typedef __attribute__((ext_vector_type(4))) __bf16 bf16x4;
typedef __attribute__((ext_vector_type(2))) long   longx2;

__device__ __forceinline__ void gload_lds16(const void* g, void* l) {
  __builtin_amdgcn_global_load_lds(
      (const __attribute__((address_space(1))) void*)g,
      (__attribute__((address_space(3))) void*)l, 16, 0, 0);
}

// ---------------------------------------------------------------------------
// Kernel A (UNCHANGED — validated R7/R11/R12, 0 LDS conflicts downstream):
// fused fp8-pack + prep into INTERLEAVED, swizzle-pre-applied chunk layout.
//   chunk(rb, kb) = 128 rows x 64 k-bytes; k = ks*32+g*8+b stored at
//   pos = g*16+ks*8+b; off = (r*64+pos) ^ (((r>>1)&3)<<4).
// ---------------------------------------------------------------------------
__global__ __launch_bounds__(256) void koleo_pack8(const float* __restrict__ X,
                                                   float* __restrict__ sq,
                                                   unsigned int* __restrict__ minbits,
                                                   char* __restrict__ xbf) {
  const int row  = blockIdx.x * 4 + (threadIdx.x >> 6);
  const int lane = threadIdx.x & 63;
  const int rb = row >> 7, r = row & 127;
  const float* xr = X + (size_t)row * DIM;
  float s = 0.f;
#pragma unroll
  for (int i = 0; i < 3; ++i) {            // 768 = 3 * 64 lanes * 4 floats
    const int c0 = lane * 4 + i * 256;
    f32x4 v = *(const f32x4*)(xr + c0);
    s += v.x * v.x + v.y * v.y + v.z * v.z + v.w * v.w;
    int pk = __builtin_amdgcn_cvt_pk_fp8_f32(v.x, v.y, 0, false);
    pk     = __builtin_amdgcn_cvt_pk_fp8_f32(v.z, v.w, pk, true);
    const int kb = c0 >> 6;
    const int c  = c0 & 63;
    const int ks = c >> 5;
    const int g  = (c >> 3) & 3;
    const int bb = c & 7;
    const int pos = g * 16 + ks * 8 + bb;
    const int off = (r * 64 + pos) ^ (((r >> 1) & 3) << 4);
    *(int*)(xbf + (size_t)rb * FPAN + (size_t)kb * FCH + off) = pk;
  }
#pragma unroll
  for (int m = 32; m >= 1; m >>= 1) s += __shfl_xor(s, m, 64);
  if (lane == 0) {
    sq[row]      = s;
    minbits[row] = 0x7F800000u;            // +inf
  }
}

// ---------------------------------------------------------------------------
// Kernel B: 256x128 tiles (q >= 2p covers all pairs; in-tile duplicates are
// harmless under min), 8 waves (4 row-slices x 2 col-slices of 64x64 —
// per-wave geometry/addressing identical to validated R7/R12), 2-phase dbuf.
// R13 vs R12: 8-wave blocks + 48 KB LDS -> TWO independent blocks/CU
// (restores R7's cross-block stall overlap) while keeping 76% of R12's
// traffic cut (304 vs 400 MB). T5 setprio around MFMA (independent-block
// regime). Grid 1056 = 2.06 rounds at 512 concurrent (smooth like R7).
// Per epoch: stage 24 KB (3 gloads/wave), 8 ds_read_b128, 32 MFMA,
// vmcnt(0), one barrier.
// Segments: [T0 p<16:272][4 bands 16x8:512][T1 p>=16:272].
// ---------------------------------------------------------------------------
__global__ __launch_bounds__(512, 4) void koleo_t256(const char* __restrict__ xbf,
                                                     const float* __restrict__ sq,
                                                     unsigned int* __restrict__ minbits) {
  extern __shared__ char lds[];            // 49152 bytes

  // segment-ordered tile map: ti in [0,32) (256-row A panel),
  // tj in [0,64) (128-col B panel), tj >= 2*ti
  const int b = blockIdx.x;
  int ti, tj;
  if (b < 272) {                           // T0: ti in [0,16)
    int rem = b, rl = 32; ti = 0;
    while (rem >= rl) { rem -= rl; ++ti; rl -= 2; }
    tj = 2 * ti + rem;
  } else if (b < 784) {                    // bands: ti [0,16) x tj [32+8g,40+8g)
    const int idx = b - 272;
    const int g = idx >> 7, rr = idx & 127;
    ti = rr >> 3; tj = 32 + g * 8 + (rr & 7);
  } else {                                 // T1: ti in [16,32)
    int rem = b - 784, rl = 32; ti = 16;
    while (rem >= rl) { rem -= rl; ++ti; rl -= 2; }
    tj = 2 * ti + rem;
  }
  const int i0 = ti * 256, j0 = tj * 128;

  const int tid  = threadIdx.x;
  const int lane = tid & 63;
  const int wave = tid >> 6;               // 0..7
  const int wr   = wave >> 1;              // 0..3 row 64-slice of 256
  const int wc   = wave & 1;               // 0..1 col 64-slice of 128
  const int g16  = (lane >> 4) * 16;       // fragment 16B group offset

  // staging role: 24 segments of 1KB per chunk; wave stages s = wave*3+k.
  // s<16 -> A half-chunk (rb = 2ti + s/8, off (s&7)KB); else B (rb=tj).
  const char* ssrc[3];
  int sdst[3];
#pragma unroll
  for (int k = 0; k < 3; ++k) {
    const int s  = wave * 3 + k;
    const int rb = (s < 16) ? (2 * ti + (s >> 3)) : tj;
    const int of = (s < 16) ? ((s & 7) * 1024) : ((s - 16) * 1024);
    ssrc[k] = xbf + (size_t)rb * FPAN + of + lane * 16;
    sdst[k] = s * 1024;
  }

  f32x4 acc[4][4] = {};

  // ---- prologue: stage K-chunk 0 into buffer 0 ---------------------------
#pragma unroll
  for (int k = 0; k < 3; ++k)
    gload_lds16(ssrc[k], lds + sdst[k]);
  asm volatile("s_waitcnt vmcnt(0)" ::: "memory");
  __builtin_amdgcn_s_barrier();

  // ---- main K-loop: one barrier per chunk epoch ---------------------------
  for (int t = 0; t < NKB; ++t) {
    char* buf  = lds + (t & 1) * 24576;
    char* nbuf = lds + ((t + 1) & 1) * 24576;
    const bool more = (t + 1 < NKB);

    if (more) {                            // issue next-chunk staging FIRST
#pragma unroll
      for (int k = 0; k < 3; ++k)
        gload_lds16(ssrc[k] + (size_t)(t + 1) * FCH, nbuf + sdst[k]);
    }

    // 8x ds_read_b128: each 16B = [ks0 frag | ks1 frag] for one row
    longx2 aP[4], bP[4];
#pragma unroll
    for (int m = 0; m < 4; ++m) {
      const int r256 = wr * 64 + m * 16 + (lane & 15);
      const int h = r256 >> 7, rr2 = r256 & 127;
      aP[m] = *(const longx2*)(buf + h * 8192 +
                ((rr2 * 64 + g16) ^ (((rr2 >> 1) & 3) << 4)));
      const int c128 = wc * 64 + m * 16 + (lane & 15);
      bP[m] = *(const longx2*)(buf + 16384 +
                ((c128 * 64 + g16) ^ (((c128 >> 1) & 3) << 4)));
    }
    __builtin_amdgcn_s_setprio(1);
#pragma unroll
    for (int ks = 0; ks < 2; ++ks)
#pragma unroll
      for (int m = 0; m < 4; ++m)
#pragma unroll
        for (int n = 0; n < 4; ++n)
          acc[m][n] = __builtin_amdgcn_mfma_f32_16x16x32_fp8_fp8(aP[m][ks], bP[n][ks], acc[m][n], 0, 0, 0);
    __builtin_amdgcn_s_setprio(0);

    if (more) asm volatile("s_waitcnt vmcnt(0)" ::: "memory");
    __builtin_amdgcn_s_barrier();
  }

  // ---- epilogue: d2, diagonal mask, row-min + col-min, atomicMin ----------
  // C/D layout (m89, dtype-independent): col = lane&15, row = (lane>>4)*4+reg
  const int cg = lane >> 4;
  const int cl = lane & 15;
  float sqj[4], colmin[4];
#pragma unroll
  for (int n = 0; n < 4; ++n) {
    sqj[n]    = sq[j0 + wc * 64 + n * 16 + cl];
    colmin[n] = INFINITY;
  }
#pragma unroll
  for (int m = 0; m < 4; ++m) {
#pragma unroll
    for (int r = 0; r < 4; ++r) {
      const int gi = i0 + wr * 64 + m * 16 + cg * 4 + r;
      const float si = sq[gi];
      float rowmin = INFINITY;
#pragma unroll
      for (int n = 0; n < 4; ++n) {
        const int gj = j0 + wc * 64 + n * 16 + cl;
        float d2 = si + sqj[n] - 2.0f * acc[m][n][r];
        d2 = fmaxf(d2, 0.0f);
        if (gi == gj) d2 = INFINITY;
        rowmin    = fminf(rowmin, d2);
        colmin[n] = fminf(colmin[n], d2);
      }
      rowmin = fminf(rowmin, __shfl_xor(rowmin, 1, 64));
      rowmin = fminf(rowmin, __shfl_xor(rowmin, 2, 64));
      rowmin = fminf(rowmin, __shfl_xor(rowmin, 4, 64));
      rowmin = fminf(rowmin, __shfl_xor(rowmin, 8, 64));
      if (cl == 0)
        atomicMin(minbits + gi, __float_as_uint(rowmin));
    }
  }
#pragma unroll
  for (int n = 0; n < 4; ++n) {            // col-min always (dups harmless)
    float cm = colmin[n];
    cm = fminf(cm, __shfl_xor(cm, 16, 64));
    cm = fminf(cm, __shfl_xor(cm, 32, 64));
    if (cg == 0)
      atomicMin(minbits + j0 + wc * 64 + n * 16 + cl, __float_as_uint(cm));
  }
}

// ---------------------------------------------------------------------------
// Fallback (ws too small): bf16 f32-load + in-loop cvt staging, 128^2 tiles.
// ---------------------------------------------------------------------------
__global__ __launch_bounds__(256) void koleo_prep_fb(const float* __restrict__ X,
                                                     float* __restrict__ sq,
                                                     unsigned int* __restrict__ minbits) {
  const int row  = blockIdx.x * 4 + (threadIdx.x >> 6);
  const int lane = threadIdx.x & 63;
  const float* xr = X + (size_t)row * DIM;
  float s = 0.f;
#pragma unroll
  for (int i = 0; i < 3; ++i) {
    f32x4 v = *(const f32x4*)(xr + lane * 4 + i * 256);
    s += v.x * v.x + v.y * v.y + v.z * v.z + v.w * v.w;
  }
#pragma unroll
  for (int m = 32; m >= 1; m >>= 1) s += __shfl_xor(s, m, 64);
  if (lane == 0) { sq[row] = s; minbits[row] = 0x7F800000u; }
}

__global__ __launch_bounds__(256) void koleo_tile_fb(const float* __restrict__ X,
                                                     const float* __restrict__ sq,
                                                     unsigned int* __restrict__ minbits) {
  __shared__ __align__(16) char sA[16384];
  __shared__ __align__(16) char sB[16384];
  int rem = blockIdx.x, ti = 0, rowlen = NT128;
  while (rem >= rowlen) { rem -= rowlen; ++ti; --rowlen; }
  const int tj = ti + rem;
  const int i0 = ti * 128, j0 = tj * 128;
  const int tid = threadIdx.x, lane = tid & 63, wave = tid >> 6;
  const int wr = wave >> 1, wc = wave & 1;
  f32x4 acc[4][4] = {};
  for (int k0 = 0; k0 < DIM; k0 += 64) {
    __syncthreads();
#pragma unroll
    for (int it = 0; it < 8; ++it) {
      const int idx = tid + it * 256;
      const int r = idx >> 4, c4 = idx & 15;
      f32x4 va = *(const f32x4*)(X + (size_t)(i0 + r) * DIM + k0 + c4 * 4);
      f32x4 vb = *(const f32x4*)(X + (size_t)(j0 + r) * DIM + k0 + c4 * 4);
      bf16x4 ha, hb;
      ha[0] = (__bf16)va.x; ha[1] = (__bf16)va.y; ha[2] = (__bf16)va.z; ha[3] = (__bf16)va.w;
      hb[0] = (__bf16)vb.x; hb[1] = (__bf16)vb.y; hb[2] = (__bf16)vb.z; hb[3] = (__bf16)vb.w;
      int off = (r * 128 + c4 * 8) ^ ((r & 7) << 4);
      *(bf16x4*)(sA + off) = ha;
      *(bf16x4*)(sB + off) = hb;
    }
    __syncthreads();
#pragma unroll
    for (int ks = 0; ks < 2; ++ks) {
      bf16x8 af[4], bfr[4];
#pragma unroll
      for (int m = 0; m < 4; ++m) {
        const int ra = wr * 64 + m * 16 + (lane & 15);
        af[m]  = *(const bf16x8*)(sA + ((ra * 128 + ks * 64 + (lane >> 4) * 16) ^ ((ra & 7) << 4)));
        const int rb2 = wc * 64 + m * 16 + (lane & 15);
        bfr[m] = *(const bf16x8*)(sB + ((rb2 * 128 + ks * 64 + (lane >> 4) * 16) ^ ((rb2 & 7) << 4)));
      }
#pragma unroll
      for (int m = 0; m < 4; ++m)
#pragma unroll
        for (int n = 0; n < 4; ++n)
          acc[m][n] = __builtin_amdgcn_mfma_f32_16x16x32_bf16(af[m], bfr[n], acc[m][n], 0, 0, 0);
    }
  }
  const int cg = lane >> 4, cl = lane & 15;
  float sqj[4], colmin[4];
#pragma unroll
  for (int n = 0; n < 4; ++n) { sqj[n] = sq[j0 + wc * 64 + n * 16 + cl]; colmin[n] = INFINITY; }
#pragma unroll
  for (int m = 0; m < 4; ++m) {
#pragma unroll
    for (int r = 0; r < 4; ++r) {
      const int gi = i0 + wr * 64 + m * 16 + cg * 4 + r;
      const float si = sq[gi];
      float rowmin = INFINITY;
#pragma unroll
      for (int n = 0; n < 4; ++n) {
        const int gj = j0 + wc * 64 + n * 16 + cl;
        float d2 = si + sqj[n] - 2.0f * acc[m][n][r];
        d2 = fmaxf(d2, 0.0f);
        if (gi == gj) d2 = INFINITY;
        rowmin = fminf(rowmin, d2);
        colmin[n] = fminf(colmin[n], d2);
      }
      rowmin = fminf(rowmin, __shfl_xor(rowmin, 1, 64));
      rowmin = fminf(rowmin, __shfl_xor(rowmin, 2, 64));
      rowmin = fminf(rowmin, __shfl_xor(rowmin, 4, 64));
      rowmin = fminf(rowmin, __shfl_xor(rowmin, 8, 64));
      if (cl == 0) atomicMin(minbits + gi, __float_as_uint(rowmin));
    }
  }
  if (ti != tj) {
#pragma unroll
    for (int n = 0; n < 4; ++n) {
      float cm = colmin[n];
      cm = fminf(cm, __shfl_xor(cm, 16, 64));
      cm = fminf(cm, __shfl_xor(cm, 32, 64));
      if (cg == 0) atomicMin(minbits + j0 + wc * 64 + n * 16 + cl, __float_as_uint(cm));
    }
  }
}

// ---------------------------------------------------------------------------
// Final: loss = -mean(log(sqrt(min_d2) + eps)), single block
// ---------------------------------------------------------------------------
__global__ __launch_bounds__(1024) void koleo_final(const unsigned int* __restrict__ minbits,
                                                    float* __restrict__ out) {
  __shared__ float wsum[16];
  float s = 0.f;
  for (int i = threadIdx.x; i < NROWS; i += 1024) {
    float d2 = __uint_as_float(minbits[i]);
    s += logf(sqrtf(d2) + 1e-8f);
  }
#pragma unroll
  for (int m = 32; m >= 1; m >>= 1) s += __shfl_xor(s, m, 64);
  const int wv = threadIdx.x >> 6, ln = threadIdx.x & 63;
  if (ln == 0) wsum[wv] = s;
  __syncthreads();
  if (wv == 0) {
    float t = (ln < 16) ? wsum[ln] : 0.f;
#pragma unroll
    for (int m = 8; m >= 1; m >>= 1) t += __shfl_xor(t, m, 64);
    if (ln == 0) out[0] = -t / (float)NROWS;
  }
}

// ---------------------------------------------------------------------------
extern "C" void kernel_launch(void* const* d_in, const int* in_sizes, int n_in,
                              void* d_out, int out_size, void* d_ws, size_t ws_size,
                              hipStream_t stream) {
  const float* X = (const float*)d_in[0];
  float* out = (float*)d_out;
  unsigned int* minbits = (unsigned int*)d_ws;                       // 32 KB
  float* sq = (float*)((char*)d_ws + NROWS * sizeof(unsigned int));  // 32 KB
  char* xbf = (char*)d_ws + 65536;                                   // 6.29 MB

  const size_t need = 65536 + PACK8B;
  if (ws_size >= need) {
    koleo_pack8<<<NROWS / 4, 256, 0, stream>>>(X, sq, minbits, xbf);
    koleo_t256<<<NTIL3, 512, LDSB, stream>>>(xbf, sq, minbits);
  } else {
    koleo_prep_fb<<<NROWS / 4, 256, 0, stream>>>(X, sq, minbits);
    koleo_tile_fb<<<NTILES, 256, 0, stream>>>(X, sq, minbits);
  }
  koleo_final<<<1, 1024, 0, stream>>>(minbits, out);
}